// Round 3
// baseline (2686.032 us; speedup 1.0000x reference)
//
#include <hip/hip_runtime.h>

using u16 = unsigned short;
using u32 = unsigned int;
using u64 = unsigned long long;
typedef __attribute__((ext_vector_type(8))) short bf16x8;
typedef __attribute__((ext_vector_type(4))) float f32x4;

__device__ __forceinline__ u16 f2b(float f) {
  u32 u = __float_as_uint(f);
  return (u16)((u + 0x7fffu + ((u >> 16) & 1u)) >> 16);   // RNE
}

// ---------------- workspace layout (all offsets 256B-aligned) ----------------
static constexpr size_t HEX_SZ    = (size_t)513 * 512 * 4;           // tagged h-exchange, (T+1)x512 u32
static constexpr size_t OFF_HEXF0 = 0;
static constexpr size_t OFF_HEXB0 = OFF_HEXF0 + HEX_SZ;
static constexpr size_t OFF_HEXF1 = OFF_HEXB0 + HEX_SZ;
static constexpr size_t OFF_HEXB1 = OFF_HEXF1 + HEX_SZ;
static constexpr size_t OFF_LACC  = OFF_HEXB1 + HEX_SZ;              // 256 floats
static constexpr size_t ZERO_BYTES= OFF_LACC + 1024;                 // memset range
static constexpr size_t OFF_XB    = ZERO_BYTES;                      // 512x256 bf16 (embed, padded K)
static constexpr size_t OFF_WIH0F = OFF_XB    + (size_t)512*256*2;
static constexpr size_t OFF_WIH0B = OFF_WIH0F + (size_t)2048*256*2;
static constexpr size_t OFF_WIH1F = OFF_WIH0B + (size_t)2048*256*2;
static constexpr size_t OFF_WIH1B = OFF_WIH1F + (size_t)2048*1024*2;
static constexpr size_t OFF_BSALL = OFF_WIH1B + (size_t)2048*1024*2; // 8192x512 bf16 (Ws1 reordered)
static constexpr size_t OFF_BLALL = OFF_BSALL + (size_t)8192*512*2;  // 6144x512 bf16 (Wl1 reordered)
static constexpr size_t OFF_HCAT0 = OFF_BLALL + (size_t)6144*512*2;  // 512x1024 bf16
static constexpr size_t OFF_HCAT1 = OFF_HCAT0 + (size_t)512*1024*2;
static constexpr size_t OFF_XG0F  = OFF_HCAT1 + (size_t)512*1024*2;  // 512x2048 f32
static constexpr size_t OFF_XG0B  = OFF_XG0F  + (size_t)512*2048*4;
static constexpr size_t OFF_XG1F  = OFF_XG0B  + (size_t)512*2048*4;
static constexpr size_t OFF_XG1B  = OFF_XG1F  + (size_t)512*2048*4;
static constexpr size_t OFF_PFS   = OFF_XG1B  + (size_t)512*2048*4;  // 512x4096 f32
static constexpr size_t OFF_PBS   = OFF_PFS   + (size_t)512*4096*4;
static constexpr size_t OFF_PFL   = OFF_PBS   + (size_t)512*4096*4;  // 512x3072 f32
static constexpr size_t OFF_PBL   = OFF_PFL   + (size_t)512*3072*4;

// ---------------- embedding: x[t] = [W_word[w], W_tag[tg], 0-pad] as bf16 (K padded 250->256) ----
__global__ __launch_bounds__(64) void k_embed(const int* __restrict__ wi, const int* __restrict__ ti,
                                              const float* __restrict__ Ww, const float* __restrict__ Wt,
                                              u16* __restrict__ x) {
  int t = blockIdx.x;
  int w = wi[t], tg = ti[t];
  for (int c = threadIdx.x; c < 256; c += 64) {
    float v = 0.f;
    if (c < 200) v = Ww[(size_t)w * 200 + c];
    else if (c < 250) v = Wt[(size_t)tg * 50 + (c - 200)];
    x[(size_t)t * 256 + c] = f2b(v);
  }
}

// ---------------- layer-0 Wih cast (pad 250->256), both directions in one launch --------------
__global__ __launch_bounds__(256) void k_prep0(const float* __restrict__ sf, const float* __restrict__ sb,
                                               u16* __restrict__ df, u16* __restrict__ db) {
  int stride = gridDim.x * 256;
  for (int i = blockIdx.x * 256 + threadIdx.x; i < 2048 * 256; i += stride) {
    int n = i >> 8, k = i & 255;
    df[i] = (k < 250) ? f2b(sf[(size_t)n * 250 + k]) : (u16)0;
    db[i] = (k < 250) ? f2b(sb[(size_t)n * 250 + k]) : (u16)0;
  }
}

// ---------------- bf16 MFMA GEMM body: C(MxN) = A(MxK) @ B(NxK)^T (+bias) ----------------
#define AST 40  // LDS row stride in ushorts (80B = 5*16B, conflict-free b128 reads)
__device__ __forceinline__ void gemm_body(const u16* __restrict__ A, int lda,
                                          const u16* __restrict__ B, int ldb,
                                          float* __restrict__ C, int ldc,
                                          const float* __restrict__ bias, int K,
                                          int m0, int n0) {
  __shared__ u16 As[128 * AST];
  __shared__ u16 Bs[128 * AST];
  int tid = threadIdx.x;
  int lane = tid & 63, wave = tid >> 6;
  int wm = wave >> 1, wn = wave & 1;
  f32x4 z = {0.f, 0.f, 0.f, 0.f};
  f32x4 acc[4][4];
#pragma unroll
  for (int i = 0; i < 4; ++i)
#pragma unroll
    for (int j = 0; j < 4; ++j) acc[i][j] = z;

  for (int k0 = 0; k0 < K; k0 += 32) {
#pragma unroll
    for (int it = 0; it < 2; ++it) {
      int c = tid + it * 256;          // 512 chunks of 8 ushorts per tile
      int row = c >> 2, cc = (c & 3) << 3;
      *(bf16x8*)&As[row * AST + cc] = *(const bf16x8*)&A[(size_t)(m0 + row) * lda + k0 + cc];
      *(bf16x8*)&Bs[row * AST + cc] = *(const bf16x8*)&B[(size_t)(n0 + row) * ldb + k0 + cc];
    }
    __syncthreads();
    int rA = lane & 15, kk = (lane >> 4) << 3;
    bf16x8 af[4], bg[4];
#pragma unroll
    for (int i = 0; i < 4; ++i) {
      af[i] = *(const bf16x8*)&As[(wm * 64 + i * 16 + rA) * AST + kk];
      bg[i] = *(const bf16x8*)&Bs[(wn * 64 + i * 16 + rA) * AST + kk];
    }
#pragma unroll
    for (int i = 0; i < 4; ++i)
#pragma unroll
      for (int j = 0; j < 4; ++j)
        acc[i][j] = __builtin_amdgcn_mfma_f32_16x16x32_bf16(af[i], bg[j], acc[i][j], 0, 0, 0);
    __syncthreads();
  }
  int rg = (lane >> 4) << 2;
#pragma unroll
  for (int i = 0; i < 4; ++i)
#pragma unroll
    for (int j = 0; j < 4; ++j) {
      int n = n0 + wn * 64 + j * 16 + (lane & 15);
      float bv = bias ? bias[n] : 0.f;
#pragma unroll
      for (int r = 0; r < 4; ++r) {
        int m = m0 + wm * 64 + i * 16 + rg + r;
        C[(size_t)m * ldc + n] = acc[i][j][r] + bv;
      }
    }
}

// paired GEMM (blockIdx.z selects set) — used for xg input GEMMs
__global__ __launch_bounds__(256) void k_gemm2(const u16* A, int lda,
                                               const u16* B0, const u16* B1, int ldb,
                                               float* C0, float* C1, int ldc,
                                               const float* bias0, const float* bias1, int K) {
  int z = blockIdx.z;
  gemm_body(A, lda, z ? B1 : B0, ldb, z ? C1 : C0, ldc, z ? bias1 : bias0, K,
            blockIdx.y * 128, blockIdx.x * 128);
}

// 4 projection GEMMs in one launch: z in {Pfs,Pbs,Pfl,Pbl}
__global__ __launch_bounds__(256) void k_proj(const u16* hcat1, const u16* bsall, const u16* blall,
                                              float* Pfs, float* Pbs, float* Pfl, float* Pbl) {
  int z = blockIdx.z;
  if (z >= 2 && blockIdx.x >= 24) return;
  const u16* A = (z & 1) ? (hcat1 + 512) : hcat1;
  const u16* B; float* C; int N;
  if (z == 0)      { B = bsall;                        C = Pfs; N = 4096; }
  else if (z == 1) { B = bsall + (size_t)4096 * 512;   C = Pbs; N = 4096; }
  else if (z == 2) { B = blall;                        C = Pfl; N = 3072; }
  else             { B = blall + (size_t)3072 * 512;   C = Pbl; N = 3072; }
  gemm_body(A, 1024, B, 512, C, N, nullptr, 512, blockIdx.y * 128, blockIdx.x * 128);
}

// ---------------- LSTM body: barrier-free wave-autonomous MFMA recurrence ----------------
// 16 WGs/dir x 256 thr (4 waves). Wave w owns 8 units (all 4 gates): rows gate*512+u0+8w+(col&7),
// gate = 2*ntl + (col>>3). Weights resident in VGPRs (bfr[2][16] = 128 VGPRs).
// Each wave polls ALL 512 tagged words (4 x u64/lane, pipelined), stages h in its own
// parity-double-buffered LDS plane -> zero __syncthreads in the step loop.
__device__ __forceinline__ void lstm_body(const float* __restrict__ xg_f, const float* __restrict__ xg_b,
                                          const float* __restrict__ whh_f, const float* __restrict__ whh_b,
                                          u32* __restrict__ hex_f, u32* __restrict__ hex_b,
                                          u16* __restrict__ hcat) {
  __shared__ __align__(16) u16 hw[4][2][512];   // per-wave, parity double-buffered (8 KB)
  int bid = blockIdx.x;
  int dir = bid >> 4, slice = bid & 15;
  const float* xg  = dir ? xg_b : xg_f;
  const float* whh = dir ? whh_b : whh_f;
  u32* hex = dir ? hex_b : hex_f;
  int u0 = slice * 32;
  int tid = threadIdx.x;
  int wave = tid >> 6, lane = tid & 63;
  int col = lane & 15, kgrp = lane >> 4;
  int uw = u0 + 8 * wave;                       // this wave's 8 units

  // ---- prologue: load this thread's 32 B-fragments of Whh into registers ----
  bf16x8 bfr[2][16];
#pragma unroll
  for (int ntl = 0; ntl < 2; ++ntl) {
    int gate = 2 * ntl + (col >> 3);
    int row = gate * 512 + uw + (col & 7);
    const float* wr = whh + (size_t)row * 512;
#pragma unroll
    for (int kt = 0; kt < 16; ++kt) {
      int k0 = kt * 32 + kgrp * 8;
      f32x4 w0 = *(const f32x4*)&wr[k0];
      f32x4 w1 = *(const f32x4*)&wr[k0 + 4];
      bf16x8 v;
      v[0] = (short)f2b(w0.x); v[1] = (short)f2b(w0.y);
      v[2] = (short)f2b(w0.z); v[3] = (short)f2b(w0.w);
      v[4] = (short)f2b(w1.x); v[5] = (short)f2b(w1.y);
      v[6] = (short)f2b(w1.z); v[7] = (short)f2b(w1.w);
      bfr[ntl][kt] = v;
    }
  }

  const u64 TAGM = 0x0000FFFF0000FFFFull;
  float creg = 0.f;
  for (int s = 0; s < 512; ++s) {
    int t = dir ? (511 - s) : s;
    int rrow = dir ? (t + 1) : t;
    int par = s & 1;

    // xg prefetch (independent of h) — latency hides under the poll
    const float* xr = &xg[(size_t)t * 2048 + uw + (lane & 7)];
    float xga = xr[0], xgb2 = xr[512], xgc = xr[1024], xgd = xr[1536];

    // poll all 512 words: 4 u64 loads per lane, all in flight per iteration
    const u64* hp = (const u64*)(hex + (size_t)rrow * 512) + lane * 4;
    u64 expct = (u64)(u32)s | ((u64)(u32)s << 32);
    u64 w0, w1, w2, w3;
    do {
      w0 = __hip_atomic_load(hp + 0, __ATOMIC_RELAXED, __HIP_MEMORY_SCOPE_AGENT);
      w1 = __hip_atomic_load(hp + 1, __ATOMIC_RELAXED, __HIP_MEMORY_SCOPE_AGENT);
      w2 = __hip_atomic_load(hp + 2, __ATOMIC_RELAXED, __HIP_MEMORY_SCOPE_AGENT);
      w3 = __hip_atomic_load(hp + 3, __ATOMIC_RELAXED, __HIP_MEMORY_SCOPE_AGENT);
    } while (((w0 & TAGM) != expct) | ((w1 & TAGM) != expct) |
             ((w2 & TAGM) != expct) | ((w3 & TAGM) != expct));

    // stage h into this wave's LDS plane (lane covers units lane*8..lane*8+7)
    bf16x8 hv;
    hv[0] = (short)(u16)(w0 >> 16); hv[1] = (short)(u16)(w0 >> 48);
    hv[2] = (short)(u16)(w1 >> 16); hv[3] = (short)(u16)(w1 >> 48);
    hv[4] = (short)(u16)(w2 >> 16); hv[5] = (short)(u16)(w2 >> 48);
    hv[6] = (short)(u16)(w3 >> 16); hv[7] = (short)(u16)(w3 >> 48);
    *(bf16x8*)&hw[wave][par][lane * 8] = hv;

    // MFMA matvec: every D row = h . Whh^T slice (A rows all = h)
    const u16* hb = &hw[wave][par][0];
    f32x4 z4 = {0.f, 0.f, 0.f, 0.f};
    f32x4 acc0[4], acc1[4];
#pragma unroll
    for (int q = 0; q < 4; ++q) { acc0[q] = z4; acc1[q] = z4; }
#pragma unroll
    for (int kt = 0; kt < 16; ++kt) {
      bf16x8 a = *(const bf16x8*)&hb[kt * 32 + kgrp * 8];   // broadcast within 16-lane group
      acc0[kt & 3] = __builtin_amdgcn_mfma_f32_16x16x32_bf16(a, bfr[0][kt], acc0[kt & 3], 0, 0, 0);
      acc1[kt & 3] = __builtin_amdgcn_mfma_f32_16x16x32_bf16(a, bfr[1][kt], acc1[kt & 3], 0, 0, 0);
    }
    float v0 = acc0[0].x + acc0[1].x + acc0[2].x + acc0[3].x;   // gate (col>>3)   for unit uw+(col&7)
    float v1 = acc1[0].x + acc1[1].x + acc1[2].x + acc1[3].x;   // gate 2+(col>>3) for unit uw+(col&7)
    float gfv = __shfl_xor(v0, 8);
    float gov = __shfl_xor(v1, 8);
    if (lane < 8) {
      float gi = v0 + xga, gf = gfv + xgb2, gg = v1 + xgc, go = gov + xgd;
      float iv = __builtin_amdgcn_rcpf(1.f + __expf(-gi));
      float fv = __builtin_amdgcn_rcpf(1.f + __expf(-gf));
      float gv = 1.f - 2.f * __builtin_amdgcn_rcpf(__expf(2.f * gg) + 1.f);
      float ov = __builtin_amdgcn_rcpf(1.f + __expf(-go));
      creg = fv * creg + iv * gv;
      float h = ov * (1.f - 2.f * __builtin_amdgcn_rcpf(__expf(2.f * creg) + 1.f));
      u16 hb16 = f2b(h);
      int wrow = dir ? t : (t + 1);
      u32 word = ((u32)hb16 << 16) | (u32)(s + 1);
      __hip_atomic_store(&hex[(size_t)wrow * 512 + uw + lane], word, __ATOMIC_RELAXED, __HIP_MEMORY_SCOPE_AGENT);
      hcat[(size_t)t * 1024 + dir * 512 + uw + lane] = hb16;
    }
  }
}

__global__ __launch_bounds__(256, 1) void k_lstm(const float* __restrict__ xg_f, const float* __restrict__ xg_b,
                                                 const float* __restrict__ whh_f, const float* __restrict__ whh_b,
                                                 u32* __restrict__ hex_f, u32* __restrict__ hex_b,
                                                 u16* __restrict__ hcat) {
  lstm_body(xg_f, xg_b, whh_f, whh_b, hex_f, hex_b, hcat);
}

// layer-0 LSTM + fused prep (layer-1 Wih cast, Ws1/Wl1 reorders) on idle CUs
__global__ __launch_bounds__(256, 1) void k_lstm_fused(const float* __restrict__ xg_f, const float* __restrict__ xg_b,
                                                       const float* __restrict__ whh_f, const float* __restrict__ whh_b,
                                                       u32* __restrict__ hex_f, u32* __restrict__ hex_b,
                                                       u16* __restrict__ hcat,
                                                       const float* __restrict__ Wih_l1f, const float* __restrict__ Wih_l1b,
                                                       u16* __restrict__ wih1f, u16* __restrict__ wih1b,
                                                       const float* __restrict__ Ws1, u16* __restrict__ bsall,
                                                       const float* __restrict__ Wl1, u16* __restrict__ blall) {
  if (blockIdx.x < 32) {
    lstm_body(xg_f, xg_b, whh_f, whh_b, hex_f, hex_b, hcat);
    return;
  }
  int pid = blockIdx.x - 32;
  int nb = gridDim.x - 32;
  int i0 = pid * 256 + threadIdx.x, stride = nb * 256;
  for (int i = i0; i < 2048 * 1024; i += stride) {
    wih1f[i] = f2b(Wih_l1f[i]);
    wih1b[i] = f2b(Wih_l1b[i]);
  }
  for (int i = i0; i < 8 * 1024 * 512; i += stride) {
    int u = i & 511, nidx = i >> 9, k = nidx >> 10, h = nidx & 1023;
    bsall[i] = f2b(Ws1[(size_t)h * 4096 + k * 512 + u]);
  }
  for (int i = i0; i < 6 * 1024 * 512; i += stride) {
    int u = i & 511, nidx = i >> 9, k = nidx >> 10, h = nidx & 1023;
    blall[i] = f2b(Wl1[(size_t)h * 3072 + k * 512 + u]);
  }
}

// ---------------- span loss: gather proj rows, relu, head matvec, log-softmax NLL ----------------
template <int KSP, int C>
__device__ __forceinline__ void span_body(int blk,
                                          const float* __restrict__ Pf, const float* __restrict__ Pb,
                                          const int* __restrict__ lefts, const int* __restrict__ rights,
                                          const int* __restrict__ tgts, const float* __restrict__ b1,
                                          const float* __restrict__ W2, const float* __restrict__ b2,
                                          float* __restrict__ loss_acc) {
  constexpr int NP = KSP * 1024;
  __shared__ float hid[4][1024];
  __shared__ float sc[4][64];
  int tid = threadIdx.x;
  int n0 = blk * 4;
  int d = tid * 4;
  f32x4 bv = *(const f32x4*)&b1[d];
#pragma unroll
  for (int ss = 0; ss < 4; ++ss) {
    int n = n0 + ss;
    f32x4 acc = bv;
#pragma unroll
    for (int k = 0; k < KSP; ++k) {
      int l = lefts[n * KSP + k], r = rights[n * KSP + k];
      f32x4 a1 = *(const f32x4*)&Pf[(size_t)r * NP + k * 1024 + d];
      f32x4 a2 = *(const f32x4*)&Pf[(size_t)(l - 1) * NP + k * 1024 + d];
      f32x4 a3 = *(const f32x4*)&Pb[(size_t)l * NP + k * 1024 + d];
      f32x4 a4 = *(const f32x4*)&Pb[(size_t)(r + 1) * NP + k * 1024 + d];
      acc += a1 - a2 + a3 - a4;
    }
    acc.x = fmaxf(acc.x, 0.f); acc.y = fmaxf(acc.y, 0.f);
    acc.z = fmaxf(acc.z, 0.f); acc.w = fmaxf(acc.w, 0.f);
    *(f32x4*)&hid[ss][d] = acc;
  }
  __syncthreads();
  int wave = tid >> 6, lane = tid & 63;
  for (int c = wave; c < C; c += 4) {
    float p0 = 0.f, p1 = 0.f, p2 = 0.f, p3 = 0.f;
    for (int i = lane; i < 1024; i += 64) {
      float w = W2[(size_t)c * 1024 + i];
      p0 += hid[0][i] * w; p1 += hid[1][i] * w; p2 += hid[2][i] * w; p3 += hid[3][i] * w;
    }
#pragma unroll
    for (int o = 32; o; o >>= 1) {
      p0 += __shfl_xor(p0, o); p1 += __shfl_xor(p1, o);
      p2 += __shfl_xor(p2, o); p3 += __shfl_xor(p3, o);
    }
    if (lane == 0) {
      sc[0][c] = p0 + b2[c]; sc[1][c] = p1 + b2[c];
      sc[2][c] = p2 + b2[c]; sc[3][c] = p3 + b2[c];
    }
  }
  __syncthreads();
  {
    int s = wave;
    float v = (lane < C) ? sc[s][lane] : -1e30f;
    float m = v;
#pragma unroll
    for (int o = 32; o; o >>= 1) m = fmaxf(m, __shfl_xor(m, o));
    float e = (lane < C) ? __expf(v - m) : 0.f;
#pragma unroll
    for (int o = 32; o; o >>= 1) e += __shfl_xor(e, o);
    if (lane == 0) {
      int tg = tgts[n0 + s];
      float loss = m + __logf(e) - sc[s][tg];
      atomicAdd(&loss_acc[(n0 + s) & 255], loss);
    }
  }
}

__global__ __launch_bounds__(256) void k_span_fused(const float* Pfs, const float* Pbs,
                                                    const int* s_l, const int* s_r, const int* s_tgt,
                                                    const float* bs1, const float* Ws2, const float* bs2,
                                                    const float* Pfl, const float* Pbl,
                                                    const int* l_l, const int* l_r, const int* l_tgt,
                                                    const float* bl1, const float* Wl2, const float* bl2,
                                                    float* lacc) {
  if (blockIdx.x < 2048)
    span_body<4, 2>(blockIdx.x, Pfs, Pbs, s_l, s_r, s_tgt, bs1, Ws2, bs2, lacc);
  else
    span_body<3, 56>(blockIdx.x - 2048, Pfl, Pbl, l_l, l_r, l_tgt, bl1, Wl2, bl2, lacc);
}

__global__ __launch_bounds__(256) void k_finalize(const float* __restrict__ acc, float* __restrict__ out) {
  int tid = threadIdx.x;
  __shared__ float s[4];
  float v = acc[tid];
#pragma unroll
  for (int o = 32; o; o >>= 1) v += __shfl_xor(v, o);
  if ((tid & 63) == 0) s[tid >> 6] = v;
  __syncthreads();
  if (tid == 0) out[0] = (s[0] + s[1] + s[2] + s[3]) * (1.0f / 16384.0f);
}

extern "C" void kernel_launch(void* const* d_in, const int* in_sizes, int n_in,
                              void* d_out, int out_size, void* d_ws, size_t ws_size,
                              hipStream_t stream) {
  (void)in_sizes; (void)n_in; (void)out_size; (void)ws_size;
  const int* word_inds = (const int*)d_in[0];
  const int* tag_inds  = (const int*)d_in[1];
  const int* s_tgt = (const int*)d_in[2];
  const int* l_tgt = (const int*)d_in[3];
  const int* s_l = (const int*)d_in[4];
  const int* s_r = (const int*)d_in[5];
  const int* l_l = (const int*)d_in[6];
  const int* l_r = (const int*)d_in[7];
  const float* W_word  = (const float*)d_in[8];
  const float* W_tag   = (const float*)d_in[9];
  const float* Wih_l0f = (const float*)d_in[10];
  const float* Whh_l0f = (const float*)d_in[11];
  const float* b_l0f   = (const float*)d_in[12];
  const float* Wih_l0b = (const float*)d_in[13];
  const float* Whh_l0b = (const float*)d_in[14];
  const float* b_l0b   = (const float*)d_in[15];
  const float* Wih_l1f = (const float*)d_in[16];
  const float* Whh_l1f = (const float*)d_in[17];
  const float* b_l1f   = (const float*)d_in[18];
  const float* Wih_l1b = (const float*)d_in[19];
  const float* Whh_l1b = (const float*)d_in[20];
  const float* b_l1b   = (const float*)d_in[21];
  const float* Ws1 = (const float*)d_in[22];
  const float* bs1 = (const float*)d_in[23];
  const float* Ws2 = (const float*)d_in[24];
  const float* bs2 = (const float*)d_in[25];
  const float* Wl1 = (const float*)d_in[26];
  const float* bl1 = (const float*)d_in[27];
  const float* Wl2 = (const float*)d_in[28];
  const float* bl2 = (const float*)d_in[29];

  char* ws = (char*)d_ws;
  u32* hexf0 = (u32*)(ws + OFF_HEXF0);
  u32* hexb0 = (u32*)(ws + OFF_HEXB0);
  u32* hexf1 = (u32*)(ws + OFF_HEXF1);
  u32* hexb1 = (u32*)(ws + OFF_HEXB1);
  float* lacc = (float*)(ws + OFF_LACC);
  u16* xb    = (u16*)(ws + OFF_XB);
  u16* wih0f = (u16*)(ws + OFF_WIH0F);
  u16* wih0b = (u16*)(ws + OFF_WIH0B);
  u16* wih1f = (u16*)(ws + OFF_WIH1F);
  u16* wih1b = (u16*)(ws + OFF_WIH1B);
  u16* bsall = (u16*)(ws + OFF_BSALL);
  u16* blall = (u16*)(ws + OFF_BLALL);
  u16* hcat0 = (u16*)(ws + OFF_HCAT0);
  u16* hcat1 = (u16*)(ws + OFF_HCAT1);
  float* xg0f = (float*)(ws + OFF_XG0F);
  float* xg0b = (float*)(ws + OFF_XG0B);
  float* xg1f = (float*)(ws + OFF_XG1F);
  float* xg1b = (float*)(ws + OFF_XG1B);
  float* Pfs = (float*)(ws + OFF_PFS);
  float* Pbs = (float*)(ws + OFF_PBS);
  float* Pfl = (float*)(ws + OFF_PFL);
  float* Pbl = (float*)(ws + OFF_PBL);

  // zero the tagged h-exchange buffers (boundary rows + tags) and loss accumulators
  hipMemsetAsync(ws, 0, ZERO_BYTES, stream);

  // prep: embed + layer-0 weight cast
  k_embed<<<512, 64, 0, stream>>>(word_inds, tag_inds, W_word, W_tag, xb);
  k_prep0<<<512, 256, 0, stream>>>(Wih_l0f, Wih_l0b, wih0f, wih0b);

  // layer 0 input GEMMs (both directions, one launch)
  k_gemm2<<<dim3(16, 4, 2), 256, 0, stream>>>(xb, 256, wih0f, wih0b, 256, xg0f, xg0b, 2048, b_l0f, b_l0b, 256);
  // layer 0 recurrence + fused prep of layer-1/projection weights
  k_lstm_fused<<<544, 256, 0, stream>>>(xg0f, xg0b, Whh_l0f, Whh_l0b, hexf0, hexb0, hcat0,
                                        Wih_l1f, Wih_l1b, wih1f, wih1b, Ws1, bsall, Wl1, blall);
  // layer 1 input GEMMs
  k_gemm2<<<dim3(16, 4, 2), 256, 0, stream>>>(hcat0, 1024, wih1f, wih1b, 1024, xg1f, xg1b, 2048, b_l1f, b_l1b, 1024);
  // layer 1 recurrence
  k_lstm<<<32, 256, 0, stream>>>(xg1f, xg1b, Whh_l1f, Whh_l1b, hexf1, hexb1, hcat1);

  // per-position projection tables (4 GEMMs, one launch)
  k_proj<<<dim3(32, 4, 4), 256, 0, stream>>>(hcat1, bsall, blall, Pfs, Pbs, Pfl, Pbl);

  // span losses (both heads, one launch) + final mean
  k_span_fused<<<4096, 256, 0, stream>>>(Pfs, Pbs, s_l, s_r, s_tgt, bs1, Ws2, bs2,
                                         Pfl, Pbl, l_l, l_r, l_tgt, bl1, Wl2, bl2, lacc);
  k_finalize<<<1, 256, 0, stream>>>(lacc, (float*)d_out);
}

// Round 4
// 2007.754 us; speedup vs baseline: 1.3378x; 1.3378x over previous
//
#include <hip/hip_runtime.h>

using u16 = unsigned short;
using u32 = unsigned int;
using u64 = unsigned long long;
typedef __attribute__((ext_vector_type(8))) short bf16x8;
typedef __attribute__((ext_vector_type(4))) float f32x4;

__device__ __forceinline__ u16 f2b(float f) {
  u32 u = __float_as_uint(f);
  return (u16)((u + 0x7fffu + ((u >> 16) & 1u)) >> 16);   // RNE
}

// ---------------- workspace layout (all offsets 256B-aligned) ----------------
static constexpr size_t HEX_SZ    = (size_t)513 * 512 * 4;           // tagged h-exchange, (T+1)x512 u32
static constexpr size_t OFF_HEXF0 = 0;
static constexpr size_t OFF_HEXB0 = OFF_HEXF0 + HEX_SZ;
static constexpr size_t OFF_HEXF1 = OFF_HEXB0 + HEX_SZ;
static constexpr size_t OFF_HEXB1 = OFF_HEXF1 + HEX_SZ;
static constexpr size_t OFF_LACC  = OFF_HEXB1 + HEX_SZ;              // 256 floats
static constexpr size_t OFF_CLAIM = OFF_LACC + 1024;                 // 2 x 16 u32 claim blocks
static constexpr size_t OFF_PROG  = OFF_CLAIM + 256;                 // 4 x 256KB progress (f0,b0,f1,b1)
static constexpr size_t ZERO_BYTES= OFF_PROG + 4 * 262144;           // memset range (~5.3MB)
static constexpr size_t OFF_XB    = ZERO_BYTES;                      // 512x256 bf16 (embed, padded K)
static constexpr size_t OFF_WIH0F = OFF_XB    + (size_t)512*256*2;
static constexpr size_t OFF_WIH0B = OFF_WIH0F + (size_t)2048*256*2;
static constexpr size_t OFF_WIH1F = OFF_WIH0B + (size_t)2048*256*2;
static constexpr size_t OFF_WIH1B = OFF_WIH1F + (size_t)2048*1024*2;
static constexpr size_t OFF_BSALL = OFF_WIH1B + (size_t)2048*1024*2; // 8192x512 bf16 (Ws1 reordered)
static constexpr size_t OFF_BLALL = OFF_BSALL + (size_t)8192*512*2;  // 6144x512 bf16 (Wl1 reordered)
static constexpr size_t OFF_HCAT0 = OFF_BLALL + (size_t)6144*512*2;  // 512x1024 bf16
static constexpr size_t OFF_HCAT1 = OFF_HCAT0 + (size_t)512*1024*2;
static constexpr size_t OFF_XG0F  = OFF_HCAT1 + (size_t)512*1024*2;  // 512x2048 f32
static constexpr size_t OFF_XG0B  = OFF_XG0F  + (size_t)512*2048*4;
static constexpr size_t OFF_XG1F  = OFF_XG0B  + (size_t)512*2048*4;
static constexpr size_t OFF_XG1B  = OFF_XG1F  + (size_t)512*2048*4;
static constexpr size_t OFF_PFS   = OFF_XG1B  + (size_t)512*2048*4;  // 512x4096 f32
static constexpr size_t OFF_PBS   = OFF_PFS   + (size_t)512*4096*4;
static constexpr size_t OFF_PFL   = OFF_PBS   + (size_t)512*4096*4;  // 512x3072 f32
static constexpr size_t OFF_PBL   = OFF_PFL   + (size_t)512*3072*4;

// ---------------- embedding: x[t] = [W_word[w], W_tag[tg], 0-pad] as bf16 (K padded 250->256) ----
__global__ __launch_bounds__(64) void k_embed(const int* __restrict__ wi, const int* __restrict__ ti,
                                              const float* __restrict__ Ww, const float* __restrict__ Wt,
                                              u16* __restrict__ x) {
  int t = blockIdx.x;
  int w = wi[t], tg = ti[t];
  for (int c = threadIdx.x; c < 256; c += 64) {
    float v = 0.f;
    if (c < 200) v = Ww[(size_t)w * 200 + c];
    else if (c < 250) v = Wt[(size_t)tg * 50 + (c - 200)];
    x[(size_t)t * 256 + c] = f2b(v);
  }
}

// ---------------- all weight casts / reorders in one kernel ----------------
__global__ __launch_bounds__(256) void k_prep_all(const float* __restrict__ Wih_l0f, const float* __restrict__ Wih_l0b,
                                                  u16* __restrict__ wih0f, u16* __restrict__ wih0b,
                                                  const float* __restrict__ Wih_l1f, const float* __restrict__ Wih_l1b,
                                                  u16* __restrict__ wih1f, u16* __restrict__ wih1b,
                                                  const float* __restrict__ Ws1, u16* __restrict__ bsall,
                                                  const float* __restrict__ Wl1, u16* __restrict__ blall) {
  int i0 = blockIdx.x * 256 + threadIdx.x, stride = gridDim.x * 256;
  for (int i = i0; i < 2048 * 256; i += stride) {
    int n = i >> 8, k = i & 255;
    wih0f[i] = (k < 250) ? f2b(Wih_l0f[(size_t)n * 250 + k]) : (u16)0;
    wih0b[i] = (k < 250) ? f2b(Wih_l0b[(size_t)n * 250 + k]) : (u16)0;
  }
  for (int i = i0; i < 2048 * 1024; i += stride) {
    wih1f[i] = f2b(Wih_l1f[i]);
    wih1b[i] = f2b(Wih_l1b[i]);
  }
  for (int i = i0; i < 8 * 1024 * 512; i += stride) {
    int u = i & 511, nidx = i >> 9, k = nidx >> 10, h = nidx & 1023;
    bsall[i] = f2b(Ws1[(size_t)h * 4096 + k * 512 + u]);
  }
  for (int i = i0; i < 6 * 1024 * 512; i += stride) {
    int u = i & 511, nidx = i >> 9, k = nidx >> 10, h = nidx & 1023;
    blall[i] = f2b(Wl1[(size_t)h * 3072 + k * 512 + u]);
  }
}

// ---------------- bf16 MFMA GEMM body: C(MxN) = A(MxK) @ B(NxK)^T (+bias) ----------------
#define AST 40  // LDS row stride in ushorts (80B = 5*16B, conflict-free b128 reads)
__device__ __forceinline__ void gemm_body(const u16* __restrict__ A, int lda,
                                          const u16* __restrict__ B, int ldb,
                                          float* __restrict__ C, int ldc,
                                          const float* __restrict__ bias, int K,
                                          int m0, int n0) {
  __shared__ u16 As[128 * AST];
  __shared__ u16 Bs[128 * AST];
  int tid = threadIdx.x;
  int lane = tid & 63, wave = tid >> 6;
  int wm = wave >> 1, wn = wave & 1;
  f32x4 z = {0.f, 0.f, 0.f, 0.f};
  f32x4 acc[4][4];
#pragma unroll
  for (int i = 0; i < 4; ++i)
#pragma unroll
    for (int j = 0; j < 4; ++j) acc[i][j] = z;

  for (int k0 = 0; k0 < K; k0 += 32) {
#pragma unroll
    for (int it = 0; it < 2; ++it) {
      int c = tid + it * 256;          // 512 chunks of 8 ushorts per tile
      int row = c >> 2, cc = (c & 3) << 3;
      *(bf16x8*)&As[row * AST + cc] = *(const bf16x8*)&A[(size_t)(m0 + row) * lda + k0 + cc];
      *(bf16x8*)&Bs[row * AST + cc] = *(const bf16x8*)&B[(size_t)(n0 + row) * ldb + k0 + cc];
    }
    __syncthreads();
    int rA = lane & 15, kk = (lane >> 4) << 3;
    bf16x8 af[4], bg[4];
#pragma unroll
    for (int i = 0; i < 4; ++i) {
      af[i] = *(const bf16x8*)&As[(wm * 64 + i * 16 + rA) * AST + kk];
      bg[i] = *(const bf16x8*)&Bs[(wn * 64 + i * 16 + rA) * AST + kk];
    }
#pragma unroll
    for (int i = 0; i < 4; ++i)
#pragma unroll
      for (int j = 0; j < 4; ++j)
        acc[i][j] = __builtin_amdgcn_mfma_f32_16x16x32_bf16(af[i], bg[j], acc[i][j], 0, 0, 0);
    __syncthreads();
  }
  int rg = (lane >> 4) << 2;
#pragma unroll
  for (int i = 0; i < 4; ++i)
#pragma unroll
    for (int j = 0; j < 4; ++j) {
      int n = n0 + wn * 64 + j * 16 + (lane & 15);
      float bv = bias ? bias[n] : 0.f;
#pragma unroll
      for (int r = 0; r < 4; ++r) {
        int m = m0 + wm * 64 + i * 16 + rg + r;
        C[(size_t)m * ldc + n] = acc[i][j][r] + bv;
      }
    }
}

// paired GEMM (blockIdx.z selects set) — used for xg input GEMMs
__global__ __launch_bounds__(256) void k_gemm2(const u16* A, int lda,
                                               const u16* B0, const u16* B1, int ldb,
                                               float* C0, float* C1, int ldc,
                                               const float* bias0, const float* bias1, int K) {
  int z = blockIdx.z;
  gemm_body(A, lda, z ? B1 : B0, ldb, z ? C1 : C0, ldc, z ? bias1 : bias0, K,
            blockIdx.y * 128, blockIdx.x * 128);
}

// 4 projection GEMMs in one launch: z in {Pfs,Pbs,Pfl,Pbl}
__global__ __launch_bounds__(256) void k_proj(const u16* hcat1, const u16* bsall, const u16* blall,
                                              float* Pfs, float* Pbs, float* Pfl, float* Pbl) {
  int z = blockIdx.z;
  if (z >= 2 && blockIdx.x >= 24) return;
  const u16* A = (z & 1) ? (hcat1 + 512) : hcat1;
  const u16* B; float* C; int N;
  if (z == 0)      { B = bsall;                        C = Pfs; N = 4096; }
  else if (z == 1) { B = bsall + (size_t)4096 * 512;   C = Pbs; N = 4096; }
  else if (z == 2) { B = blall;                        C = Pfl; N = 3072; }
  else             { B = blall + (size_t)3072 * 512;   C = Pbl; N = 3072; }
  gemm_body(A, 1024, B, 512, C, N, nullptr, 512, blockIdx.y * 128, blockIdx.x * 128);
}

// ---------------- LSTM core: MFMA recurrence, dual sync protocol ----------------
// FAST: all 16 WGs of a direction verified co-resident on ONE XCD -> exchange via the
//   shared per-XCD L2 with plain loads/stores (L1 write-through; data rows are
//   first-touch per CU). Detection via 64-replica progress counters (4KB stride ->
//   same L1 set -> guaranteed eviction); replica 0 published/polled at agent scope
//   as a liveness rescue. Ordering: data stores -> __syncthreads (vmcnt drain) ->
//   wave0 publishes progress.
// SLOW: agent-scope tagged-word protocol (measured-correct rounds 2/3).
template <bool FAST>
__device__ __forceinline__ void lstm_core(int dir, int slice,
                                          const float* __restrict__ xg, const float* __restrict__ whh,
                                          u32* __restrict__ hex, u32* __restrict__ prog,
                                          u16* __restrict__ hcat) {
  __shared__ __align__(16) u16 hw[4][2][512];   // per-wave, parity double-buffered
  int tid = threadIdx.x;
  int wave = tid >> 6, lane = tid & 63;
  int col = lane & 15, kgrp = lane >> 4;
  int u0 = slice * 32;
  int uw = u0 + 8 * wave;                       // this wave's 8 units

  // ---- prologue: load this thread's 32 B-fragments of Whh into registers ----
  bf16x8 bfr[2][16];
#pragma unroll
  for (int ntl = 0; ntl < 2; ++ntl) {
    int gate = 2 * ntl + (col >> 3);
    int row = gate * 512 + uw + (col & 7);
    const float* wr = whh + (size_t)row * 512;
#pragma unroll
    for (int kt = 0; kt < 16; ++kt) {
      int k0 = kt * 32 + kgrp * 8;
      f32x4 w0 = *(const f32x4*)&wr[k0];
      f32x4 w1 = *(const f32x4*)&wr[k0 + 4];
      bf16x8 v;
      v[0] = (short)f2b(w0.x); v[1] = (short)f2b(w0.y);
      v[2] = (short)f2b(w0.z); v[3] = (short)f2b(w0.w);
      v[4] = (short)f2b(w1.x); v[5] = (short)f2b(w1.y);
      v[6] = (short)f2b(w1.z); v[7] = (short)f2b(w1.w);
      bfr[ntl][kt] = v;
    }
  }

  const u64 TAGM = 0x0000FFFF0000FFFFull;
  float creg = 0.f;
  u32 it = (u32)(slice * 4 + wave);   // decorrelate replica start across consumers
  for (int s = 0; s < 512; ++s) {
    int t = dir ? (511 - s) : s;
    int rrow = dir ? (t + 1) : t;
    int par = s & 1;

    // xg prefetch (independent of h) — latency hides under the poll
    const float* xr = &xg[(size_t)t * 2048 + uw + (lane & 7)];
    float xga = xr[0], xgb2 = xr[512], xgc = xr[1024], xgd = xr[1536];

    u64 w0, w1, w2, w3;
    if constexpr (FAST) {
      // poll progress (one 64B line per round, from L2); replica 0 = agent rescue
      for (;;) {
        u32 idx = (it++) & 63u;
        u32 p;
        if (idx == 0u)
          p = __hip_atomic_load(&prog[lane & 15], __ATOMIC_RELAXED, __HIP_MEMORY_SCOPE_AGENT);
        else
          p = __hip_atomic_load(&prog[(size_t)idx * 1024 + (lane & 15)], __ATOMIC_RELAXED, __HIP_MEMORY_SCOPE_WORKGROUP);
        if (__all((int)(p >= (u32)s))) break;
      }
      asm volatile("" ::: "memory");
      const u64* hp = (const u64*)(hex + (size_t)rrow * 512) + lane * 4;
      w0 = __hip_atomic_load(hp + 0, __ATOMIC_RELAXED, __HIP_MEMORY_SCOPE_WORKGROUP);
      w1 = __hip_atomic_load(hp + 1, __ATOMIC_RELAXED, __HIP_MEMORY_SCOPE_WORKGROUP);
      w2 = __hip_atomic_load(hp + 2, __ATOMIC_RELAXED, __HIP_MEMORY_SCOPE_WORKGROUP);
      w3 = __hip_atomic_load(hp + 3, __ATOMIC_RELAXED, __HIP_MEMORY_SCOPE_WORKGROUP);
    } else {
      const u64* hp = (const u64*)(hex + (size_t)rrow * 512) + lane * 4;
      u64 expct = (u64)(u32)s | ((u64)(u32)s << 32);
      do {
        w0 = __hip_atomic_load(hp + 0, __ATOMIC_RELAXED, __HIP_MEMORY_SCOPE_AGENT);
        w1 = __hip_atomic_load(hp + 1, __ATOMIC_RELAXED, __HIP_MEMORY_SCOPE_AGENT);
        w2 = __hip_atomic_load(hp + 2, __ATOMIC_RELAXED, __HIP_MEMORY_SCOPE_AGENT);
        w3 = __hip_atomic_load(hp + 3, __ATOMIC_RELAXED, __HIP_MEMORY_SCOPE_AGENT);
      } while (((w0 & TAGM) != expct) | ((w1 & TAGM) != expct) |
               ((w2 & TAGM) != expct) | ((w3 & TAGM) != expct));
    }

    // stage h into this wave's LDS plane (lane covers units lane*8..lane*8+7)
    bf16x8 hv;
    hv[0] = (short)(u16)(w0 >> 16); hv[1] = (short)(u16)(w0 >> 48);
    hv[2] = (short)(u16)(w1 >> 16); hv[3] = (short)(u16)(w1 >> 48);
    hv[4] = (short)(u16)(w2 >> 16); hv[5] = (short)(u16)(w2 >> 48);
    hv[6] = (short)(u16)(w3 >> 16); hv[7] = (short)(u16)(w3 >> 48);
    *(bf16x8*)&hw[wave][par][lane * 8] = hv;

    // MFMA matvec: every D row = h . Whh^T slice (A rows all = h)
    const u16* hb = &hw[wave][par][0];
    f32x4 z4 = {0.f, 0.f, 0.f, 0.f};
    f32x4 acc0[4], acc1[4];
#pragma unroll
    for (int q = 0; q < 4; ++q) { acc0[q] = z4; acc1[q] = z4; }
#pragma unroll
    for (int kt = 0; kt < 16; ++kt) {
      bf16x8 a = *(const bf16x8*)&hb[kt * 32 + kgrp * 8];   // broadcast within 16-lane group
      acc0[kt & 3] = __builtin_amdgcn_mfma_f32_16x16x32_bf16(a, bfr[0][kt], acc0[kt & 3], 0, 0, 0);
      acc1[kt & 3] = __builtin_amdgcn_mfma_f32_16x16x32_bf16(a, bfr[1][kt], acc1[kt & 3], 0, 0, 0);
    }
    float v0 = acc0[0].x + acc0[1].x + acc0[2].x + acc0[3].x;   // gate (col>>3)   for unit uw+(col&7)
    float v1 = acc1[0].x + acc1[1].x + acc1[2].x + acc1[3].x;   // gate 2+(col>>3) for unit uw+(col&7)
    float gfv = __shfl_xor(v0, 8);
    float gov = __shfl_xor(v1, 8);
    if (lane < 8) {
      float gi = v0 + xga, gf = gfv + xgb2, gg = v1 + xgc, go = gov + xgd;
      float iv = __builtin_amdgcn_rcpf(1.f + __expf(-gi));
      float fv = __builtin_amdgcn_rcpf(1.f + __expf(-gf));
      float gv = 1.f - 2.f * __builtin_amdgcn_rcpf(__expf(2.f * gg) + 1.f);
      float ov = __builtin_amdgcn_rcpf(1.f + __expf(-go));
      creg = fv * creg + iv * gv;
      float h = ov * (1.f - 2.f * __builtin_amdgcn_rcpf(__expf(2.f * creg) + 1.f));
      u16 hb16 = f2b(h);
      int wrow = dir ? t : (t + 1);
      u32 word = ((u32)hb16 << 16) | (u32)(s + 1);
      if constexpr (FAST)
        __hip_atomic_store(&hex[(size_t)wrow * 512 + uw + lane], word, __ATOMIC_RELAXED, __HIP_MEMORY_SCOPE_WORKGROUP);
      else
        __hip_atomic_store(&hex[(size_t)wrow * 512 + uw + lane], word, __ATOMIC_RELAXED, __HIP_MEMORY_SCOPE_AGENT);
      hcat[(size_t)t * 1024 + dir * 512 + uw + lane] = hb16;
    }
    if constexpr (FAST) {
      __syncthreads();   // drains vmcnt: all 4 waves' data stores are in L2 before publish
      if (wave == 0) {
        if (lane == 0)
          __hip_atomic_store(&prog[slice], (u32)(s + 1), __ATOMIC_RELAXED, __HIP_MEMORY_SCOPE_AGENT);
        else
          __hip_atomic_store(&prog[(size_t)lane * 1024 + slice], (u32)(s + 1), __ATOMIC_RELAXED, __HIP_MEMORY_SCOPE_WORKGROUP);
      }
    }
  }
}

__global__ __launch_bounds__(256, 1) void k_lstm(const float* __restrict__ xg_f, const float* __restrict__ xg_b,
                                                 const float* __restrict__ whh_f, const float* __restrict__ whh_b,
                                                 u32* __restrict__ hex_f, u32* __restrict__ hex_b,
                                                 u32* __restrict__ claim,
                                                 u32* __restrict__ prog_f, u32* __restrict__ prog_b,
                                                 u16* __restrict__ hcat) {
  __shared__ int sh[3];   // dir (-1 = exit), slice, fast
  if (threadIdx.x == 0) {
    u32 xcd;
    asm volatile("s_getreg_b32 %0, hwreg(HW_REG_XCC_ID)" : "=s"(xcd));
    xcd &= 7u;
    u32 slot = __hip_atomic_fetch_add(&claim[xcd], 1u, __ATOMIC_RELAXED, __HIP_MEMORY_SCOPE_AGENT);
    u32 tot  = __hip_atomic_fetch_add(&claim[8], 1u, __ATOMIC_ACQ_REL, __HIP_MEMORY_SCOPE_AGENT);
    if (tot == (u32)gridDim.x - 1u) {
      u32 c0 = __hip_atomic_load(&claim[0], __ATOMIC_RELAXED, __HIP_MEMORY_SCOPE_AGENT);
      u32 c1 = __hip_atomic_load(&claim[1], __ATOMIC_RELAXED, __HIP_MEMORY_SCOPE_AGENT);
      __hip_atomic_store(&claim[9], (c0 >= 16u && c1 >= 16u) ? 1u : 2u,
                         __ATOMIC_RELEASE, __HIP_MEMORY_SCOPE_AGENT);
    }
    u32 m;
    do { m = __hip_atomic_load(&claim[9], __ATOMIC_ACQUIRE, __HIP_MEMORY_SCOPE_AGENT); } while (m == 0u);
    int dir = -1, slice = 0;
    if (m == 1u) {
      if (xcd == 0u && slot < 16u)      { dir = 0; slice = (int)slot; }
      else if (xcd == 1u && slot < 16u) { dir = 1; slice = (int)slot; }
    } else {
      u32 s2 = __hip_atomic_fetch_add(&claim[10], 1u, __ATOMIC_RELAXED, __HIP_MEMORY_SCOPE_AGENT);
      if (s2 < 32u) { dir = (int)(s2 >> 4); slice = (int)(s2 & 15u); }
    }
    sh[0] = dir; sh[1] = slice; sh[2] = (m == 1u) ? 1 : 0;
  }
  __syncthreads();
  int dir = sh[0], slice = sh[1], fast = sh[2];
  if (dir < 0) return;
  const float* xg  = dir ? xg_b : xg_f;
  const float* whh = dir ? whh_b : whh_f;
  u32* hex  = dir ? hex_b : hex_f;
  u32* prog = dir ? prog_b : prog_f;
  if (fast) lstm_core<true>(dir, slice, xg, whh, hex, prog, hcat);
  else      lstm_core<false>(dir, slice, xg, whh, hex, prog, hcat);
}

// ---------------- span loss: gather proj rows, relu, head matvec, log-softmax NLL ----------------
template <int KSP, int C>
__device__ __forceinline__ void span_body(int blk,
                                          const float* __restrict__ Pf, const float* __restrict__ Pb,
                                          const int* __restrict__ lefts, const int* __restrict__ rights,
                                          const int* __restrict__ tgts, const float* __restrict__ b1,
                                          const float* __restrict__ W2, const float* __restrict__ b2,
                                          float* __restrict__ loss_acc) {
  constexpr int NP = KSP * 1024;
  __shared__ float hid[4][1024];
  __shared__ float sc[4][64];
  int tid = threadIdx.x;
  int n0 = blk * 4;
  int d = tid * 4;
  f32x4 bv = *(const f32x4*)&b1[d];
#pragma unroll
  for (int ss = 0; ss < 4; ++ss) {
    int n = n0 + ss;
    f32x4 acc = bv;
#pragma unroll
    for (int k = 0; k < KSP; ++k) {
      int l = lefts[n * KSP + k], r = rights[n * KSP + k];
      f32x4 a1 = *(const f32x4*)&Pf[(size_t)r * NP + k * 1024 + d];
      f32x4 a2 = *(const f32x4*)&Pf[(size_t)(l - 1) * NP + k * 1024 + d];
      f32x4 a3 = *(const f32x4*)&Pb[(size_t)l * NP + k * 1024 + d];
      f32x4 a4 = *(const f32x4*)&Pb[(size_t)(r + 1) * NP + k * 1024 + d];
      acc += a1 - a2 + a3 - a4;
    }
    acc.x = fmaxf(acc.x, 0.f); acc.y = fmaxf(acc.y, 0.f);
    acc.z = fmaxf(acc.z, 0.f); acc.w = fmaxf(acc.w, 0.f);
    *(f32x4*)&hid[ss][d] = acc;
  }
  __syncthreads();
  int wave = tid >> 6, lane = tid & 63;
  for (int c = wave; c < C; c += 4) {
    float p0 = 0.f, p1 = 0.f, p2 = 0.f, p3 = 0.f;
    for (int i = lane; i < 1024; i += 64) {
      float w = W2[(size_t)c * 1024 + i];
      p0 += hid[0][i] * w; p1 += hid[1][i] * w; p2 += hid[2][i] * w; p3 += hid[3][i] * w;
    }
#pragma unroll
    for (int o = 32; o; o >>= 1) {
      p0 += __shfl_xor(p0, o); p1 += __shfl_xor(p1, o);
      p2 += __shfl_xor(p2, o); p3 += __shfl_xor(p3, o);
    }
    if (lane == 0) {
      sc[0][c] = p0 + b2[c]; sc[1][c] = p1 + b2[c];
      sc[2][c] = p2 + b2[c]; sc[3][c] = p3 + b2[c];
    }
  }
  __syncthreads();
  {
    int s = wave;
    float v = (lane < C) ? sc[s][lane] : -1e30f;
    float m = v;
#pragma unroll
    for (int o = 32; o; o >>= 1) m = fmaxf(m, __shfl_xor(m, o));
    float e = (lane < C) ? __expf(v - m) : 0.f;
#pragma unroll
    for (int o = 32; o; o >>= 1) e += __shfl_xor(e, o);
    if (lane == 0) {
      int tg = tgts[n0 + s];
      float loss = m + __logf(e) - sc[s][tg];
      atomicAdd(&loss_acc[(n0 + s) & 255], loss);
    }
  }
}

__global__ __launch_bounds__(256) void k_span_fused(const float* Pfs, const float* Pbs,
                                                    const int* s_l, const int* s_r, const int* s_tgt,
                                                    const float* bs1, const float* Ws2, const float* bs2,
                                                    const float* Pfl, const float* Pbl,
                                                    const int* l_l, const int* l_r, const int* l_tgt,
                                                    const float* bl1, const float* Wl2, const float* bl2,
                                                    float* lacc) {
  if (blockIdx.x < 2048)
    span_body<4, 2>(blockIdx.x, Pfs, Pbs, s_l, s_r, s_tgt, bs1, Ws2, bs2, lacc);
  else
    span_body<3, 56>(blockIdx.x - 2048, Pfl, Pbl, l_l, l_r, l_tgt, bl1, Wl2, bl2, lacc);
}

__global__ __launch_bounds__(256) void k_finalize(const float* __restrict__ acc, float* __restrict__ out) {
  int tid = threadIdx.x;
  __shared__ float s[4];
  float v = acc[tid];
#pragma unroll
  for (int o = 32; o; o >>= 1) v += __shfl_xor(v, o);
  if ((tid & 63) == 0) s[tid >> 6] = v;
  __syncthreads();
  if (tid == 0) out[0] = (s[0] + s[1] + s[2] + s[3]) * (1.0f / 16384.0f);
}

extern "C" void kernel_launch(void* const* d_in, const int* in_sizes, int n_in,
                              void* d_out, int out_size, void* d_ws, size_t ws_size,
                              hipStream_t stream) {
  (void)in_sizes; (void)n_in; (void)out_size; (void)ws_size;
  const int* word_inds = (const int*)d_in[0];
  const int* tag_inds  = (const int*)d_in[1];
  const int* s_tgt = (const int*)d_in[2];
  const int* l_tgt = (const int*)d_in[3];
  const int* s_l = (const int*)d_in[4];
  const int* s_r = (const int*)d_in[5];
  const int* l_l = (const int*)d_in[6];
  const int* l_r = (const int*)d_in[7];
  const float* W_word  = (const float*)d_in[8];
  const float* W_tag   = (const float*)d_in[9];
  const float* Wih_l0f = (const float*)d_in[10];
  const float* Whh_l0f = (const float*)d_in[11];
  const float* b_l0f   = (const float*)d_in[12];
  const float* Wih_l0b = (const float*)d_in[13];
  const float* Whh_l0b = (const float*)d_in[14];
  const float* b_l0b   = (const float*)d_in[15];
  const float* Wih_l1f = (const float*)d_in[16];
  const float* Whh_l1f = (const float*)d_in[17];
  const float* b_l1f   = (const float*)d_in[18];
  const float* Wih_l1b = (const float*)d_in[19];
  const float* Whh_l1b = (const float*)d_in[20];
  const float* b_l1b   = (const float*)d_in[21];
  const float* Ws1 = (const float*)d_in[22];
  const float* bs1 = (const float*)d_in[23];
  const float* Ws2 = (const float*)d_in[24];
  const float* bs2 = (const float*)d_in[25];
  const float* Wl1 = (const float*)d_in[26];
  const float* bl1 = (const float*)d_in[27];
  const float* Wl2 = (const float*)d_in[28];
  const float* bl2 = (const float*)d_in[29];

  char* ws = (char*)d_ws;
  u32* hexf0 = (u32*)(ws + OFF_HEXF0);
  u32* hexb0 = (u32*)(ws + OFF_HEXB0);
  u32* hexf1 = (u32*)(ws + OFF_HEXF1);
  u32* hexb1 = (u32*)(ws + OFF_HEXB1);
  float* lacc = (float*)(ws + OFF_LACC);
  u32* claim0 = (u32*)(ws + OFF_CLAIM);
  u32* claim1 = (u32*)(ws + OFF_CLAIM + 64);
  u32* progf0 = (u32*)(ws + OFF_PROG);
  u32* progb0 = (u32*)(ws + OFF_PROG + 262144);
  u32* progf1 = (u32*)(ws + OFF_PROG + 2 * 262144);
  u32* progb1 = (u32*)(ws + OFF_PROG + 3 * 262144);
  u16* xb    = (u16*)(ws + OFF_XB);
  u16* wih0f = (u16*)(ws + OFF_WIH0F);
  u16* wih0b = (u16*)(ws + OFF_WIH0B);
  u16* wih1f = (u16*)(ws + OFF_WIH1F);
  u16* wih1b = (u16*)(ws + OFF_WIH1B);
  u16* bsall = (u16*)(ws + OFF_BSALL);
  u16* blall = (u16*)(ws + OFF_BLALL);
  u16* hcat0 = (u16*)(ws + OFF_HCAT0);
  u16* hcat1 = (u16*)(ws + OFF_HCAT1);
  float* xg0f = (float*)(ws + OFF_XG0F);
  float* xg0b = (float*)(ws + OFF_XG0B);
  float* xg1f = (float*)(ws + OFF_XG1F);
  float* xg1b = (float*)(ws + OFF_XG1B);
  float* Pfs = (float*)(ws + OFF_PFS);
  float* Pbs = (float*)(ws + OFF_PBS);
  float* Pfl = (float*)(ws + OFF_PFL);
  float* Pbl = (float*)(ws + OFF_PBL);

  // zero: hex buffers (boundary rows + tags), loss acc, claim blocks, progress counters
  hipMemsetAsync(ws, 0, ZERO_BYTES, stream);

  // prep: embed + all weight casts/reorders
  k_embed<<<512, 64, 0, stream>>>(word_inds, tag_inds, W_word, W_tag, xb);
  k_prep_all<<<1024, 256, 0, stream>>>(Wih_l0f, Wih_l0b, wih0f, wih0b,
                                       Wih_l1f, Wih_l1b, wih1f, wih1b,
                                       Ws1, bsall, Wl1, blall);

  // layer 0 input GEMMs (both directions, one launch)
  k_gemm2<<<dim3(16, 4, 2), 256, 0, stream>>>(xb, 256, wih0f, wih0b, 256, xg0f, xg0b, 2048, b_l0f, b_l0b, 256);
  // layer 0 recurrence
  k_lstm<<<256, 256, 0, stream>>>(xg0f, xg0b, Whh_l0f, Whh_l0b, hexf0, hexb0, claim0, progf0, progb0, hcat0);
  // layer 1 input GEMMs
  k_gemm2<<<dim3(16, 4, 2), 256, 0, stream>>>(hcat0, 1024, wih1f, wih1b, 1024, xg1f, xg1b, 2048, b_l1f, b_l1b, 1024);
  // layer 1 recurrence
  k_lstm<<<256, 256, 0, stream>>>(xg1f, xg1b, Whh_l1f, Whh_l1b, hexf1, hexb1, claim1, progf1, progb1, hcat1);

  // per-position projection tables (4 GEMMs, one launch)
  k_proj<<<dim3(32, 4, 4), 256, 0, stream>>>(hcat1, bsall, blall, Pfs, Pbs, Pfl, Pbl);

  // span losses (both heads, one launch) + final mean
  k_span_fused<<<4096, 256, 0, stream>>>(Pfs, Pbs, s_l, s_r, s_tgt, bs1, Ws2, bs2,
                                         Pfl, Pbl, l_l, l_r, l_tgt, bl1, Wl2, bl2, lacc);
  k_finalize<<<1, 256, 0, stream>>>(lacc, (float*)d_out);
}